// Round 4
// baseline (134.482 us; speedup 1.0000x reference)
//
#include <hip/hip_runtime.h>
#include <hip/hip_bf16.h>

#define BATCH 4
#define CCH   256
#define SS    2304          // 48*48
#define NHEAD 8
#define HD    32
// fold 1/sqrt(32) * log2(e) into Q so softmax is raw exp2
#define SCALE_L2E (1.4426950408889634f * 0.17677669529663687f)

using bf16x8 = __attribute__((ext_vector_type(8))) short;
using v4s    = __attribute__((ext_vector_type(4))) short;
using f32x4  = __attribute__((ext_vector_type(4))) float;

static __device__ __forceinline__ unsigned short f2bf(float f) {
    union { float f; unsigned u; } a; a.f = f;
    unsigned r = a.u + 0x7fff + ((a.u >> 16) & 1);   // RNE
    return (unsigned short)(r >> 16);
}
static __device__ __forceinline__ unsigned pk2(float a, float b) {
    return (unsigned)f2bf(a) | ((unsigned)f2bf(b) << 16);
}
// native packed f32->bf16 (compiler emits v_cvt_pk_bf16_f32)
static __device__ __forceinline__ v4s pack4(float a, float b, float c, float d) {
    float2 lo; lo.x = a; lo.y = b;
    float2 hi; hi.x = c; hi.y = d;
    union { __hip_bfloat162 h2[2]; v4s s; } u;
    u.h2[0] = __float22bfloat162_rn(lo);
    u.h2[1] = __float22bfloat162_rn(hi);
    return u.s;
}

// ---------------- W fp32 -> bf16 (Wq|Wk|Wv stacked, Wo separate) ----------------
__global__ __launch_bounds__(256) void wconv(const float* __restrict__ Wq, const float* __restrict__ Wk,
                                             const float* __restrict__ Wv, const float* __restrict__ Wo,
                                             unsigned short* __restrict__ wqkv, unsigned short* __restrict__ wo) {
    const int idx = blockIdx.x * 256 + threadIdx.x;
    if (idx < 768 * 256) {
        const int o = idx >> 8, c = idx & 255;
        const float v = (o < 256) ? Wq[idx] : (o < 512) ? Wk[(o - 256) * 256 + c] : Wv[(o - 512) * 256 + c];
        wqkv[idx] = f2bf(v);
    } else {
        const int j = idx - 768 * 256;
        wo[j] = f2bf(Wo[j]);
    }
}

// ---------------- x [b][c][s] fp32 -> xt [b][s][c] bf16 (tiled transpose) ----------------
__global__ __launch_bounds__(256) void xtrans(const float* __restrict__ x, unsigned short* __restrict__ xt) {
    __shared__ float T[64][65];
    const int b = blockIdx.z, c0 = blockIdx.y * 64, s0 = blockIdx.x * 64;
    const int tid = threadIdx.x;
    #pragma unroll
    for (int p = 0; p < 16; ++p) {
        const int c = p * 4 + (tid >> 6), s = tid & 63;
        T[c][s] = x[((size_t)(b * CCH + c0 + c)) * SS + s0 + s];
    }
    __syncthreads();
    #pragma unroll
    for (int p = 0; p < 8; ++p) {
        const int s = p * 8 + (tid >> 5), c = (tid & 31) * 2;
        *(unsigned*)&xt[((size_t)(b * SS + s0 + s)) * CCH + c0 + c] = pk2(T[c][s], T[c + 1][s]);
    }
}

// ---------------- fused QKV GEMM (bf16 MFMA, barrier-free) ----------------
__global__ __launch_bounds__(256) void gemm_qkv(const unsigned short* __restrict__ xt,
                                                const unsigned short* __restrict__ wqkv,
                                                const float* __restrict__ bq, const float* __restrict__ bk,
                                                const float* __restrict__ bv,
                                                unsigned short* __restrict__ qt, unsigned short* __restrict__ kt,
                                                unsigned short* __restrict__ vp) {
    __shared__ char Eb[4][9216];           // per-wave epilogue staging
    const int b  = blockIdx.z;
    const int o0 = blockIdx.x * 64, s0 = blockIdx.y * 128;
    const int tid = threadIdx.x, wid = tid >> 6, lane = tid & 63;
    const int lr = lane & 15, lg = lane >> 4;
    const int o_w = o0 + (wid & 1) * 32, s_w = s0 + (wid >> 1) * 64;

    const f32x4 zero4 = {0.f, 0.f, 0.f, 0.f};
    f32x4 acc[2][4];
    #pragma unroll
    for (int ai = 0; ai < 2; ++ai)
        #pragma unroll
        for (int bj = 0; bj < 4; ++bj) acc[ai][bj] = zero4;

    #pragma unroll
    for (int c0 = 0; c0 < 256; c0 += 32) {
        bf16x8 a[2], bb[4];
        #pragma unroll
        for (int ai = 0; ai < 2; ++ai)
            a[ai] = *(const bf16x8*)&wqkv[(size_t)(o_w + ai * 16 + lr) * 256 + c0 + lg * 8];
        #pragma unroll
        for (int bj = 0; bj < 4; ++bj)
            bb[bj] = *(const bf16x8*)&xt[((size_t)b * SS + s_w + bj * 16 + lr) * 256 + c0 + lg * 8];
        #pragma unroll
        for (int ai = 0; ai < 2; ++ai)
            #pragma unroll
            for (int bj = 0; bj < 4; ++bj)
                acc[ai][bj] = __builtin_amdgcn_mfma_f32_16x16x32_bf16(a[ai], bb[bj], acc[ai][bj], 0, 0, 0);
    }

    const int t = o0 >> 8;                 // 0=Q 1=K 2=V
    const int o_loc = o_w - t * 256;
    const float* bias = (t == 0) ? bq : (t == 1) ? bk : bv;

    float vals[2][4][4];
    #pragma unroll
    for (int ai = 0; ai < 2; ++ai)
        #pragma unroll
        for (int bj = 0; bj < 4; ++bj)
            #pragma unroll
            for (int i = 0; i < 4; ++i) {
                float vv = acc[ai][bj][i] + bias[o_loc + ai * 16 + 4 * lg + i];
                if (t == 0) vv *= SCALE_L2E;
                vals[ai][bj][i] = vv;
            }

    if (t < 2) {
        unsigned short* dst = (t == 0) ? qt : kt;
        unsigned short* Ls = (unsigned short*)Eb[wid];   // [64 s][40 o] bf16
        #pragma unroll
        for (int ai = 0; ai < 2; ++ai)
            #pragma unroll
            for (int bj = 0; bj < 4; ++bj) {
                uint2 w;
                w.x = pk2(vals[ai][bj][0], vals[ai][bj][1]);
                w.y = pk2(vals[ai][bj][2], vals[ai][bj][3]);
                *(uint2*)&Ls[(bj * 16 + lr) * 40 + ai * 16 + 4 * lg] = w;
            }
        const int h = o_loc >> 5;
        const size_t base = (size_t)(b * NHEAD + h) * SS;
        #pragma unroll
        for (int p = 0; p < 4; ++p) {
            const int cid = p * 64 + lane;
            const int s_loc = cid >> 2, oc = cid & 3;
            uint4 v = *(const uint4*)&Ls[s_loc * 40 + oc * 8];
            *(uint4*)&dst[(base + s_w + s_loc) * HD + oc * 8] = v;
        }
    } else {
        float* Lf = (float*)Eb[wid];                      // [32 o][68 s] f32
        #pragma unroll
        for (int ai = 0; ai < 2; ++ai)
            #pragma unroll
            for (int bj = 0; bj < 4; ++bj)
                #pragma unroll
                for (int i = 0; i < 4; ++i)
                    Lf[(ai * 16 + 4 * lg + i) * 68 + bj * 16 + lr] = vals[ai][bj][i];
        #pragma unroll
        for (int p = 0; p < 4; ++p) {
            const int cid = p * 64 + lane;
            const int oc = cid >> 3, sc8 = (cid & 7) * 8;
            float4 f0 = *(const float4*)&Lf[oc * 68 + sc8];
            float4 f1 = *(const float4*)&Lf[oc * 68 + sc8 + 4];
            uint4 w;
            w.x = pk2(f0.x, f0.y); w.y = pk2(f0.z, f0.w);
            w.z = pk2(f1.x, f1.y); w.w = pk2(f1.z, f1.w);
            *(uint4*)&vp[((size_t)(b * CCH) + o_loc + oc) * SS + s_w + sc8] = w;
        }
    }
}

// ---------------- MFMA flash attention v3: P stays in registers ----------------
// qt,kt: bf16 [bh][s][d]; vp: bf16 [b][c][s]; ot: bf16 [b][s][c]
// Swapped QK^T (mfma16x16x32: A=K, B=Q) -> lane holds P[q=lr][t=4lg+i].
// PV as O^T = V^T x P^T via mfma_16x16x16bf16_1k: B-frag k-slots = 4lg+j == D layout. No exchange.
// Block = 2 waves, split-K over t (1152 each), q-tile 64; combine via small LDS.

#define ATT_LOAD(KF, VF, T0) do {                                                          \
    _Pragma("unroll") for (int tt = 0; tt < 4; ++tt)                                       \
        KF[tt] = *(const bf16x8*)&ktb[(size_t)((T0) + tt * 16 + lr) * HD + lg * 8];        \
    _Pragma("unroll") for (int tt = 0; tt < 4; ++tt)                                       \
        _Pragma("unroll") for (int dh = 0; dh < 2; ++dh)                                   \
            VF[tt][dh] = *(const v4s*)&vb[(size_t)(dh * 16 + lr) * SS + (T0) + tt * 16 + 4 * lg]; \
} while (0)

#define ATT_COMPUTE(KF, VF) do {                                                           \
    _Pragma("unroll") for (int qh = 0; qh < 4; ++qh) {                                     \
        _Pragma("unroll") for (int tt = 0; tt < 4; ++tt) {                                 \
            f32x4 sc = __builtin_amdgcn_mfma_f32_16x16x32_bf16(KF[tt], qf[qh], zero4, 0, 0, 0); \
            const float p0 = __builtin_amdgcn_exp2f(sc[0]);                                \
            const float p1 = __builtin_amdgcn_exp2f(sc[1]);                                \
            const float p2 = __builtin_amdgcn_exp2f(sc[2]);                                \
            const float p3 = __builtin_amdgcn_exp2f(sc[3]);                                \
            psum[qh] += (p0 + p1) + (p2 + p3);                                             \
            const v4s pf = pack4(p0, p1, p2, p3);                                          \
            acc[qh][0] = __builtin_amdgcn_mfma_f32_16x16x16bf16_1k(VF[tt][0], pf, acc[qh][0], 0, 0, 0); \
            acc[qh][1] = __builtin_amdgcn_mfma_f32_16x16x16bf16_1k(VF[tt][1], pf, acc[qh][1], 0, 0, 0); \
        }                                                                                  \
    }                                                                                      \
} while (0)

__global__ __launch_bounds__(128) void attn(const unsigned short* __restrict__ qt,
                                            const unsigned short* __restrict__ kt,
                                            const unsigned short* __restrict__ vp,
                                            unsigned short* __restrict__ ot) {
    __shared__ float Cmb[2][2][64][10];   // [src wave][qh slot][lane][8 O + 1 psum]

    const int tid = threadIdx.x;
    const int wid = tid >> 6, lane = tid & 63;
    const int lr = lane & 15, lg = lane >> 4;

    const int bid = blockIdx.x;            // 1152 = 8 * 144
    const int xs = bid & 7, w = bid >> 3;   // XCD swizzle: 4 bh per XCD slot
    const int bh = xs * 4 + w / 36;
    const int q0 = (w % 36) * 64;
    const int b  = bh >> 3, h = bh & 7;

    const unsigned short* qtb = qt + (size_t)bh * SS * HD;
    const unsigned short* ktb = kt + (size_t)bh * SS * HD;
    const unsigned short* vb  = vp + (size_t)(b * CCH + h * HD) * SS;

    const f32x4 zero4 = {0.f, 0.f, 0.f, 0.f};

    // Q fragments (B operand): col=lr=q, k-slots lg*8+j = d
    bf16x8 qf[4];
    #pragma unroll
    for (int qh = 0; qh < 4; ++qh)
        qf[qh] = *(const bf16x8*)&qtb[(size_t)(q0 + qh * 16 + lr) * HD + lg * 8];

    f32x4 acc[4][2];
    #pragma unroll
    for (int qh = 0; qh < 4; ++qh) { acc[qh][0] = zero4; acc[qh][1] = zero4; }
    float psum[4] = {0.f, 0.f, 0.f, 0.f};

    const int tb = wid * 1152;             // split-K: wave 0 -> [0,1152), wave 1 -> [1152,2304)

    bf16x8 kA[4], kB[4];
    v4s vA[4][2], vB[4][2];
    ATT_LOAD(kA, vA, tb);
    for (int j = 0; j < 8; ++j) {          // 18 64-t blocks: 16 in the loop + 2 epilogue
        ATT_LOAD(kB, vB, tb + (2 * j + 1) * 64);
        ATT_COMPUTE(kA, vA);
        ATT_LOAD(kA, vA, tb + (2 * j + 2) * 64);
        ATT_COMPUTE(kB, vB);
    }
    ATT_LOAD(kB, vB, tb + 17 * 64);
    ATT_COMPUTE(kA, vA);
    ATT_COMPUTE(kB, vB);

    // reduce psum over lg groups (lanes sharing lr)
    #pragma unroll
    for (int qh = 0; qh < 4; ++qh) {
        psum[qh] += __shfl_xor(psum[qh], 16);
        psum[qh] += __shfl_xor(psum[qh], 32);
    }

    // cross-wave combine: wave w finalizes qh in {2w, 2w+1}; writes the other two.
    const int ow = wid ^ 1;
    #pragma unroll
    for (int k = 0; k < 2; ++k) {
        const int qh = ow * 2 + k;
        float* rec = &Cmb[wid][k][lane][0];
        #pragma unroll
        for (int i = 0; i < 4; ++i) { rec[i] = acc[qh][0][i]; rec[4 + i] = acc[qh][1][i]; }
        rec[8] = psum[qh];
    }
    __syncthreads();
    #pragma unroll
    for (int k = 0; k < 2; ++k) {
        const int qh = wid * 2 + k;
        const float* rec = &Cmb[ow][k][lane][0];
        const float inv = 1.f / (psum[qh] + rec[8]);
        #pragma unroll
        for (int dh = 0; dh < 2; ++dh) {
            float o0 = (acc[qh][dh][0] + rec[dh * 4 + 0]) * inv;
            float o1 = (acc[qh][dh][1] + rec[dh * 4 + 1]) * inv;
            float o2 = (acc[qh][dh][2] + rec[dh * 4 + 2]) * inv;
            float o3 = (acc[qh][dh][3] + rec[dh * 4 + 3]) * inv;
            v4s sv = pack4(o0, o1, o2, o3);
            *(v4s*)&ot[((size_t)b * SS + q0 + qh * 16 + lr) * CCH + h * HD + dh * 16 + 4 * lg] = sv;
        }
    }
}

// ---------------- output GEMM: out = Wo @ ot^T + bo + x (fp32) ----------------
__global__ __launch_bounds__(256) void gemm_o(const unsigned short* __restrict__ ot,
                                              const unsigned short* __restrict__ wo,
                                              const float* __restrict__ bo, const float* __restrict__ x,
                                              float* __restrict__ out) {
    const int b  = blockIdx.z;
    const int o0 = blockIdx.x * 64, s0 = blockIdx.y * 128;
    const int tid = threadIdx.x, wid = tid >> 6, lane = tid & 63;
    const int lr = lane & 15, lg = lane >> 4;
    const int o_w = o0 + (wid & 1) * 32, s_w = s0 + (wid >> 1) * 64;

    const f32x4 zero4 = {0.f, 0.f, 0.f, 0.f};
    f32x4 acc[2][4];
    #pragma unroll
    for (int ai = 0; ai < 2; ++ai)
        #pragma unroll
        for (int bj = 0; bj < 4; ++bj) acc[ai][bj] = zero4;

    #pragma unroll
    for (int c0 = 0; c0 < 256; c0 += 32) {
        bf16x8 a[2], bb[4];
        #pragma unroll
        for (int ai = 0; ai < 2; ++ai)
            a[ai] = *(const bf16x8*)&wo[(size_t)(o_w + ai * 16 + lr) * 256 + c0 + lg * 8];
        #pragma unroll
        for (int bj = 0; bj < 4; ++bj)
            bb[bj] = *(const bf16x8*)&ot[((size_t)b * SS + s_w + bj * 16 + lr) * 256 + c0 + lg * 8];
        #pragma unroll
        for (int ai = 0; ai < 2; ++ai)
            #pragma unroll
            for (int bj = 0; bj < 4; ++bj)
                acc[ai][bj] = __builtin_amdgcn_mfma_f32_16x16x32_bf16(a[ai], bb[bj], acc[ai][bj], 0, 0, 0);
    }

    #pragma unroll
    for (int ai = 0; ai < 2; ++ai)
        #pragma unroll
        for (int bj = 0; bj < 4; ++bj)
            #pragma unroll
            for (int i = 0; i < 4; ++i) {
                const int o = o_w + ai * 16 + 4 * lg + i;
                const int s = s_w + bj * 16 + lr;
                const size_t idx = (size_t)(b * CCH + o) * SS + s;
                out[idx] = acc[ai][bj][i] + bo[o] + x[idx];
            }
}

extern "C" void kernel_launch(void* const* d_in, const int* in_sizes, int n_in,
                              void* d_out, int out_size, void* d_ws, size_t ws_size,
                              hipStream_t stream) {
    const float* x  = (const float*)d_in[0];
    const float* Wq = (const float*)d_in[1];
    const float* bq = (const float*)d_in[2];
    const float* Wk = (const float*)d_in[3];
    const float* bk = (const float*)d_in[4];
    const float* Wv = (const float*)d_in[5];
    const float* bv = (const float*)d_in[6];
    const float* Wo = (const float*)d_in[7];
    const float* bo = (const float*)d_in[8];
    float* out = (float*)d_out;

    const size_t plane = (size_t)BATCH * CCH * SS;      // 2,359,296 elems
    unsigned short* xt   = (unsigned short*)d_ws;       // [b][s][c]
    unsigned short* qtw  = xt  + plane;                 // [bh][s][d]
    unsigned short* ktw  = qtw + plane;                 // [bh][s][d]
    unsigned short* vpw  = ktw + plane;                 // [b][c][s]
    unsigned short* otw  = vpw + plane;                 // [b][s][c]
    unsigned short* wqkv = otw + plane;                 // [768][256]
    unsigned short* wob  = wqkv + 768 * 256;            // [256][256]

    wconv<<<dim3(1024), dim3(256), 0, stream>>>(Wq, Wk, Wv, Wo, wqkv, wob);
    xtrans<<<dim3(SS / 64, CCH / 64, BATCH), dim3(256), 0, stream>>>(x, xt);
    gemm_qkv<<<dim3(12, 18, BATCH), dim3(256), 0, stream>>>(xt, wqkv, bq, bk, bv, qtw, ktw, vpw);
    attn<<<dim3(1152), dim3(128), 0, stream>>>(qtw, ktw, vpw, otw);
    gemm_o<<<dim3(4, 18, BATCH), dim3(256), 0, stream>>>(otw, wob, bo, x, out);
}